// Round 1
// baseline (535.708 us; speedup 1.0000x reference)
//
#include <hip/hip_runtime.h>
#include <stdint.h>

#define NN 8192
#define CC 128
#define BN_EPS 1e-5f

__device__ inline unsigned short f2bf(float f) {
    unsigned int u = __float_as_uint(f);
    unsigned int r = (u + 0x7fffu + ((u >> 16) & 1u)) >> 16;   // RNE
    return (unsigned short)r;
}
__device__ inline float bf2f(unsigned short s) {
    return __uint_as_float(((unsigned int)s) << 16);
}

// ---------------------------------------------------------------------------
// Kernel 1: aggU = A^T @ X (unnormalized), deg[j] = rowsum(A[j,:])
// Grid (64 i-chunks, 8 j-slices) x 256 threads. A is binary {0,1} fp32.
// Each wave scans 256 rows j over a 128-wide i-chunk; ballots find nonzeros,
// LDS fp32 tile accumulates X rows, flushed with global atomics.
// HBM floor: one full read of A = 268 MB.
// ---------------------------------------------------------------------------
__global__ __launch_bounds__(256, 2) void k1_spmm(
        const float* __restrict__ A, const float* __restrict__ X,
        float* __restrict__ aggU, float* __restrict__ deg) {
    __shared__ float acc[128 * 128];          // 64 KB -> 2 blocks/CU
    const int tid  = threadIdx.x;
    const int lane = tid & 63;
    const int wave = tid >> 6;
    const int i0   = blockIdx.x * 128;
    const int jbase = blockIdx.y * 1024 + wave * 256;

    for (int t = tid; t < 128 * 128; t += 256) acc[t] = 0.0f;
    __syncthreads();

    for (int jj = 0; jj < 256; jj += 4) {
        float2 a[4]; float xa[4], xb[4];
        #pragma unroll
        for (int u = 0; u < 4; ++u) {         // batch-4 prefetch (12 loads in flight)
            int j = jbase + jj + u;
            a[u]  = *reinterpret_cast<const float2*>(A + (size_t)j * NN + i0 + lane * 2);
            xa[u] = X[j * CC + lane];
            xb[u] = X[j * CC + 64 + lane];
        }
        #pragma unroll
        for (int u = 0; u < 4; ++u) {
            int j = jbase + jj + u;
            unsigned long long m0 = __ballot(a[u].x != 0.0f);
            unsigned long long m1 = __ballot(a[u].y != 0.0f);
            int cnt = __popcll(m0) + __popcll(m1);
            if (cnt) {
                if (lane == 0) atomicAdd(&deg[j], (float)cnt);
                while (m0) {
                    int b = __builtin_ctzll(m0); m0 &= m0 - 1;
                    int row = b * 2;
                    atomicAdd(&acc[row * 128 + lane],      xa[u]);
                    atomicAdd(&acc[row * 128 + 64 + lane], xb[u]);
                }
                while (m1) {
                    int b = __builtin_ctzll(m1); m1 &= m1 - 1;
                    int row = b * 2 + 1;
                    atomicAdd(&acc[row * 128 + lane],      xa[u]);
                    atomicAdd(&acc[row * 128 + 64 + lane], xb[u]);
                }
            }
        }
    }
    __syncthreads();
    float* aggBase = aggU + (size_t)i0 * CC;
    for (int t = tid; t < 128 * 128; t += 256) atomicAdd(&aggBase[t], acc[t]);
}

// ---------------------------------------------------------------------------
// Kernel 2: h = (aggU/deg) @ Wn^T + X @ Wc^T + bn + bc, fused BN partial sums.
// Block = 256 thr: c = tid&127 (lane -> conflict-free LDS W reads), 8 rows/thr.
// W staged transposed in LDS as bf16 (64 KB total).
// ---------------------------------------------------------------------------
__global__ __launch_bounds__(256, 2) void k2_gemm(
        const float* __restrict__ aggU, const float* __restrict__ deg,
        const float* __restrict__ X,
        const float* __restrict__ Wn, const float* __restrict__ bn,
        const float* __restrict__ Wc, const float* __restrict__ bc,
        float* __restrict__ h, float* __restrict__ bsum, float* __restrict__ bsq) {
    __shared__ unsigned short WtN[128 * 128];   // WtN[k*128+c] = bf16(Wn[c,k])
    __shared__ unsigned short WtC[128 * 128];
    const int tid = threadIdx.x;
    for (int idx = tid; idx < 128 * 128; idx += 256) {
        int c = idx >> 7, k = idx & 127;
        WtN[k * 128 + c] = f2bf(Wn[idx]);
        WtC[k * 128 + c] = f2bf(Wc[idx]);
    }
    __syncthreads();
    const int c  = tid & 127;
    const int rg = tid >> 7;
    const int i0 = blockIdx.x * 16 + rg * 8;

    float accN[8], accC[8];
    #pragma unroll
    for (int r = 0; r < 8; ++r) { accN[r] = 0.0f; accC[r] = 0.0f; }

    for (int k = 0; k < 128; k += 4) {
        float4 ar[8], xr[8];
        #pragma unroll
        for (int r = 0; r < 8; ++r) {
            ar[r] = *reinterpret_cast<const float4*>(&aggU[(size_t)(i0 + r) * CC + k]);
            xr[r] = *reinterpret_cast<const float4*>(&X[(size_t)(i0 + r) * CC + k]);
        }
        #pragma unroll
        for (int kk = 0; kk < 4; ++kk) {
            float wn = bf2f(WtN[(k + kk) * 128 + c]);
            float wc = bf2f(WtC[(k + kk) * 128 + c]);
            #pragma unroll
            for (int r = 0; r < 8; ++r) {
                float av = (&ar[r].x)[kk];
                float xv = (&xr[r].x)[kk];
                accN[r] = fmaf(av, wn, accN[r]);
                accC[r] = fmaf(xv, wc, accC[r]);
            }
        }
    }

    const float bnc = bn[c], bcc = bc[c];
    float sp = 0.0f, sq = 0.0f;
    #pragma unroll
    for (int r = 0; r < 8; ++r) {
        float d  = deg[i0 + r];
        float rd = (d == 0.0f) ? 1.0f : (1.0f / d);
        float hv = accN[r] * rd + accC[r] + bnc + bcc;
        h[(size_t)(i0 + r) * CC + c] = hv;
        sp += hv; sq += hv * hv;
    }
    __syncthreads();                              // WtN reads done; reuse as fp32 scratch
    float* red = reinterpret_cast<float*>(WtN);
    red[rg * 128 + c]       = sp;
    red[256 + rg * 128 + c] = sq;
    __syncthreads();
    if (rg == 0) {
        atomicAdd(&bsum[c], red[c] + red[128 + c]);
        atomicAdd(&bsq[c],  red[256 + c] + red[384 + c]);
    }
}

// ---------------------------------------------------------------------------
// Kernel 3: out = relu(gamma * (h - mu) * rsqrt(var + eps) + beta), float4.
// mu/var recomputed per thread from the 128-channel sums (L2-hot, tiny).
// ---------------------------------------------------------------------------
__global__ __launch_bounds__(256) void k4_bn(
        const float* __restrict__ h, const float* __restrict__ bsum,
        const float* __restrict__ bsq, const float* __restrict__ gamma,
        const float* __restrict__ beta, float* __restrict__ out) {
    const int idx = (blockIdx.x * 256 + threadIdx.x) * 4;
    const int c0  = idx & 127;
    float4 hv = *reinterpret_cast<const float4*>(h + idx);
    float4 s4 = *reinterpret_cast<const float4*>(bsum + c0);
    float4 q4 = *reinterpret_cast<const float4*>(bsq + c0);
    float4 g4 = *reinterpret_cast<const float4*>(gamma + c0);
    float4 b4 = *reinterpret_cast<const float4*>(beta + c0);
    const float invN = 1.0f / 8192.0f;
    float4 o;
    const float* hp = &hv.x; const float* sp = &s4.x; const float* qp = &q4.x;
    const float* gp = &g4.x; const float* bp = &b4.x; float* op = &o.x;
    #pragma unroll
    for (int jj = 0; jj < 4; ++jj) {
        float mu  = sp[jj] * invN;
        float var = qp[jj] * invN - mu * mu;
        float sc  = gp[jj] * rsqrtf(var + BN_EPS);
        float v   = (hp[jj] - mu) * sc + bp[jj];
        op[jj] = v > 0.0f ? v : 0.0f;
    }
    *reinterpret_cast<float4*>(out + idx) = o;
}

extern "C" void kernel_launch(void* const* d_in, const int* in_sizes, int n_in,
                              void* d_out, int out_size, void* d_ws, size_t ws_size,
                              hipStream_t stream) {
    const float* X     = (const float*)d_in[0];   // [8192,128]
    const float* A     = (const float*)d_in[1];   // [8192,8192]
    const float* Wn    = (const float*)d_in[2];   // [128,128]
    const float* bn    = (const float*)d_in[3];
    const float* Wc    = (const float*)d_in[4];
    const float* bc    = (const float*)d_in[5];
    const float* gamma = (const float*)d_in[6];
    const float* beta  = (const float*)d_in[7];
    float* out = (float*)d_out;

    char* ws = (char*)d_ws;
    float* aggU = (float*)(ws);                   // 4 MB
    float* deg  = (float*)(ws + 4194304);         // 32 KB
    float* bsum = (float*)(ws + 4227072);         // 512 B
    float* bsq  = (float*)(ws + 4227584);         // 512 B
    float* h    = (float*)(ws + 4228096);         // 4 MB

    // zero the accumulated regions in one stream-ordered memset (capture-safe)
    hipMemsetAsync(d_ws, 0, 4228096, stream);

    k1_spmm<<<dim3(64, 8), 256, 0, stream>>>(A, X, aggU, deg);
    k2_gemm<<<512, 256, 0, stream>>>(aggU, deg, X, Wn, bn, Wc, bc, h, bsum, bsq);
    k4_bn<<<1024, 256, 0, stream>>>(h, bsum, bsq, gamma, beta, out);
}

// Round 2
// 529.089 us; speedup vs baseline: 1.0125x; 1.0125x over previous
//
#include <hip/hip_runtime.h>
#include <stdint.h>

#define NN 8192
#define CC 128
#define BN_EPS 1e-5f

__device__ inline unsigned short f2bf(float f) {
    unsigned int u = __float_as_uint(f);
    unsigned int r = (u + 0x7fffu + ((u >> 16) & 1u)) >> 16;   // RNE
    return (unsigned short)r;
}
__device__ inline float bf2f(unsigned short s) {
    return __uint_as_float(((unsigned int)s) << 16);
}

// ---------------------------------------------------------------------------
// Kernel 1: aggU = A^T @ X (unnormalized), deg[j] = rowsum(A[j,:]).
// Grid (64 i-chunks, 8 j-slices) x 256 thr. Per wave: 256 rows, 8 rows/batch
// via float4 A loads (lanes 0-31 = row j, lanes 32-63 = row j+1), depth-2
// register pipeline so the next batch's 4 KB is in flight while processing.
// Ballot -> uniform mask -> LDS fp32 tile atomics on the rare nonzeros.
// ---------------------------------------------------------------------------
__device__ __forceinline__ void process_pair(
        float4 a, float xa0, float xb0, float xa1, float xb1,
        int j0, float* __restrict__ acc, float* __restrict__ deg, int lane) {
    unsigned long long m0 = __ballot(a.x != 0.0f);
    unsigned long long m1 = __ballot(a.y != 0.0f);
    unsigned long long m2 = __ballot(a.z != 0.0f);
    unsigned long long m3 = __ballot(a.w != 0.0f);
    if ((m0 | m1 | m2 | m3) == 0ull) return;
    const unsigned long long LO = 0xffffffffull;
    int c0 = __popcll(m0 & LO) + __popcll(m1 & LO) + __popcll(m2 & LO) + __popcll(m3 & LO);
    int c1 = __popcll(m0 >> 32) + __popcll(m1 >> 32) + __popcll(m2 >> 32) + __popcll(m3 >> 32);
    if (lane == 0 && c0) atomicAdd(&deg[j0], (float)c0);
    if (lane == 1 && c1) atomicAdd(&deg[j0 + 1], (float)c1);
    unsigned long long m[4] = {m0, m1, m2, m3};
    #pragma unroll
    for (int comp = 0; comp < 4; ++comp) {
        unsigned int lo = (unsigned int)m[comp];
        while (lo) {
            int b = __builtin_ctz(lo); lo &= lo - 1;
            int il = 4 * b + comp;
            atomicAdd(&acc[il * 128 + lane],      xa0);
            atomicAdd(&acc[il * 128 + 64 + lane], xb0);
        }
        unsigned int hi = (unsigned int)(m[comp] >> 32);
        while (hi) {
            int b = __builtin_ctz(hi); hi &= hi - 1;
            int il = 4 * b + comp;
            atomicAdd(&acc[il * 128 + lane],      xa1);
            atomicAdd(&acc[il * 128 + 64 + lane], xb1);
        }
    }
}

#define LOADB(a_, xa_, xb_, j0_) do {                                          \
    const float* Ap_ = A + (size_t)((j0_) + (lane >> 5)) * NN + i0 + ((lane & 31) << 2); \
    _Pragma("unroll")                                                          \
    for (int u = 0; u < 4; ++u)                                                \
        a_[u] = *reinterpret_cast<const float4*>(Ap_ + (size_t)(2 * u) * NN);  \
    _Pragma("unroll")                                                          \
    for (int r = 0; r < 8; ++r) {                                              \
        xa_[r] = X[((j0_) + r) * CC + lane];                                   \
        xb_[r] = X[((j0_) + r) * CC + 64 + lane];                              \
    }                                                                          \
} while (0)

#define PROCB(a_, xa_, xb_, j0_) do {                                          \
    _Pragma("unroll")                                                          \
    for (int u = 0; u < 4; ++u)                                                \
        process_pair(a_[u], xa_[2 * u], xb_[2 * u], xa_[2 * u + 1],            \
                     xb_[2 * u + 1], (j0_) + 2 * u, acc, deg, lane);           \
} while (0)

__global__ __launch_bounds__(256, 2) void k1_spmm(
        const float* __restrict__ A, const float* __restrict__ X,
        float* __restrict__ aggU, float* __restrict__ deg) {
    __shared__ float acc[128 * 128];          // 64 KB -> 2 blocks/CU
    const int tid  = threadIdx.x;
    const int lane = tid & 63;
    const int wave = tid >> 6;
    const int i0   = blockIdx.x * 128;
    const int jbase = blockIdx.y * 1024 + wave * 256;

    for (int t = tid; t < 128 * 128; t += 256) acc[t] = 0.0f;
    __syncthreads();

    float4 a0[4], a1[4];
    float xa0[8], xb0[8], xa1[8], xb1[8];

    LOADB(a0, xa0, xb0, jbase);
    // 32 batches of 8 rows; ping-pong so the next batch is in flight.
    for (int it2 = 0; it2 < 16; ++it2) {
        int j0 = jbase + it2 * 16;
        LOADB(a1, xa1, xb1, j0 + 8);
        PROCB(a0, xa0, xb0, j0);
        if (it2 < 15) LOADB(a0, xa0, xb0, j0 + 16);
        PROCB(a1, xa1, xb1, j0 + 8);
    }

    __syncthreads();
    float* aggBase = aggU + (size_t)i0 * CC;
    for (int t = tid; t < 128 * 128; t += 256) atomicAdd(&aggBase[t], acc[t]);
}

// ---------------------------------------------------------------------------
// Kernel 2: h = (aggU/deg) @ Wn^T + X @ Wc^T + bn + bc, fused BN partial sums.
// c = tid&127 (conflict-free LDS W reads), 8 rows/thread, ping-pong k-chunk
// prefetch. W transposed in LDS as bf16 (64 KB).
// ---------------------------------------------------------------------------
__global__ __launch_bounds__(256, 2) void k2_gemm(
        const float* __restrict__ aggU, const float* __restrict__ deg,
        const float* __restrict__ X,
        const float* __restrict__ Wn, const float* __restrict__ bn,
        const float* __restrict__ Wc, const float* __restrict__ bc,
        float* __restrict__ h, float* __restrict__ bsum, float* __restrict__ bsq) {
    __shared__ unsigned short WtN[128 * 128];   // WtN[k*128+c] = bf16(Wn[c,k])
    __shared__ unsigned short WtC[128 * 128];
    const int tid = threadIdx.x;
    for (int idx = tid * 4; idx < 128 * 128; idx += 1024) {
        float4 wn4 = *reinterpret_cast<const float4*>(Wn + idx);
        float4 wc4 = *reinterpret_cast<const float4*>(Wc + idx);
        int c = idx >> 7, k0 = idx & 127;       // 4 consecutive k, same c
        WtN[(k0 + 0) * 128 + c] = f2bf(wn4.x);
        WtN[(k0 + 1) * 128 + c] = f2bf(wn4.y);
        WtN[(k0 + 2) * 128 + c] = f2bf(wn4.z);
        WtN[(k0 + 3) * 128 + c] = f2bf(wn4.w);
        WtC[(k0 + 0) * 128 + c] = f2bf(wc4.x);
        WtC[(k0 + 1) * 128 + c] = f2bf(wc4.y);
        WtC[(k0 + 2) * 128 + c] = f2bf(wc4.z);
        WtC[(k0 + 3) * 128 + c] = f2bf(wc4.w);
    }
    __syncthreads();
    const int c  = tid & 127;
    const int rg = tid >> 7;
    const int i0 = blockIdx.x * 16 + rg * 8;

    float accN[8], accC[8];
    #pragma unroll
    for (int r = 0; r < 8; ++r) { accN[r] = 0.0f; accC[r] = 0.0f; }

    float4 ar[8], xr[8], an[8], xn[8];

#define LOADK(ab_, xb_, k_) do {                                               \
    _Pragma("unroll")                                                          \
    for (int r = 0; r < 8; ++r) {                                              \
        ab_[r] = *reinterpret_cast<const float4*>(&aggU[(size_t)(i0 + r) * CC + (k_)]); \
        xb_[r] = *reinterpret_cast<const float4*>(&X[(size_t)(i0 + r) * CC + (k_)]);    \
    }                                                                          \
} while (0)

#define COMPK(ab_, xb_, k_) do {                                               \
    _Pragma("unroll")                                                          \
    for (int kk = 0; kk < 4; ++kk) {                                           \
        float wn_ = bf2f(WtN[((k_) + kk) * 128 + c]);                          \
        float wc_ = bf2f(WtC[((k_) + kk) * 128 + c]);                          \
        _Pragma("unroll")                                                      \
        for (int r = 0; r < 8; ++r) {                                          \
            accN[r] = fmaf((&ab_[r].x)[kk], wn_, accN[r]);                     \
            accC[r] = fmaf((&xb_[r].x)[kk], wc_, accC[r]);                     \
        }                                                                      \
    }                                                                          \
} while (0)

    LOADK(ar, xr, 0);
    for (int k = 0; k < 128; k += 8) {
        LOADK(an, xn, k + 4);
        COMPK(ar, xr, k);
        if (k + 8 < 128) LOADK(ar, xr, k + 8);
        COMPK(an, xn, k + 4);
    }

    const float bnc = bn[c], bcc = bc[c];
    float sp = 0.0f, sq = 0.0f;
    #pragma unroll
    for (int r = 0; r < 8; ++r) {
        float d  = deg[i0 + r];
        float rd = (d == 0.0f) ? 1.0f : (1.0f / d);
        float hv = accN[r] * rd + accC[r] + bnc + bcc;
        h[(size_t)(i0 + r) * CC + c] = hv;
        sp += hv; sq += hv * hv;
    }
    __syncthreads();                              // WtN reads done; reuse as fp32 scratch
    float* red = reinterpret_cast<float*>(WtN);
    red[rg * 128 + c]       = sp;
    red[256 + rg * 128 + c] = sq;
    __syncthreads();
    if (rg == 0) {
        atomicAdd(&bsum[c], red[c] + red[128 + c]);
        atomicAdd(&bsq[c],  red[256 + c] + red[384 + c]);
    }
}

// ---------------------------------------------------------------------------
// Kernel 3: out = relu(gamma * (h - mu) * rsqrt(var + eps) + beta), float4.
// ---------------------------------------------------------------------------
__global__ __launch_bounds__(256) void k4_bn(
        const float* __restrict__ h, const float* __restrict__ bsum,
        const float* __restrict__ bsq, const float* __restrict__ gamma,
        const float* __restrict__ beta, float* __restrict__ out) {
    const int idx = (blockIdx.x * 256 + threadIdx.x) * 4;
    const int c0  = idx & 127;
    float4 hv = *reinterpret_cast<const float4*>(h + idx);
    float4 s4 = *reinterpret_cast<const float4*>(bsum + c0);
    float4 q4 = *reinterpret_cast<const float4*>(bsq + c0);
    float4 g4 = *reinterpret_cast<const float4*>(gamma + c0);
    float4 b4 = *reinterpret_cast<const float4*>(beta + c0);
    const float invN = 1.0f / 8192.0f;
    float4 o;
    const float* hp = &hv.x; const float* sp = &s4.x; const float* qp = &q4.x;
    const float* gp = &g4.x; const float* bp = &b4.x; float* op = &o.x;
    #pragma unroll
    for (int jj = 0; jj < 4; ++jj) {
        float mu  = sp[jj] * invN;
        float var = qp[jj] * invN - mu * mu;
        float sc  = gp[jj] * rsqrtf(var + BN_EPS);
        float v   = (hp[jj] - mu) * sc + bp[jj];
        op[jj] = v > 0.0f ? v : 0.0f;
    }
    *reinterpret_cast<float4*>(out + idx) = o;
}

extern "C" void kernel_launch(void* const* d_in, const int* in_sizes, int n_in,
                              void* d_out, int out_size, void* d_ws, size_t ws_size,
                              hipStream_t stream) {
    const float* X     = (const float*)d_in[0];   // [8192,128]
    const float* A     = (const float*)d_in[1];   // [8192,8192]
    const float* Wn    = (const float*)d_in[2];   // [128,128]
    const float* bn    = (const float*)d_in[3];
    const float* Wc    = (const float*)d_in[4];
    const float* bc    = (const float*)d_in[5];
    const float* gamma = (const float*)d_in[6];
    const float* beta  = (const float*)d_in[7];
    float* out = (float*)d_out;

    char* ws = (char*)d_ws;
    float* aggU = (float*)(ws);                   // 4 MB
    float* deg  = (float*)(ws + 4194304);         // 32 KB
    float* bsum = (float*)(ws + 4227072);         // 512 B
    float* bsq  = (float*)(ws + 4227584);         // 512 B
    float* h    = (float*)(ws + 4228096);         // 4 MB

    hipMemsetAsync(d_ws, 0, 4228096, stream);

    k1_spmm<<<dim3(64, 8), 256, 0, stream>>>(A, X, aggU, deg);
    k2_gemm<<<512, 256, 0, stream>>>(aggU, deg, X, Wn, bn, Wc, bc, h, bsum, bsq);
    k4_bn<<<1024, 256, 0, stream>>>(h, bsum, bsq, gamma, beta, out);
}